// Round 1
// baseline (119.938 us; speedup 1.0000x reference)
//
#include <hip/hip_runtime.h>
#include <cstddef>

#define L1n 128
#define L2n 256
#define Kn  1024

// ---------------- Kernel 1: fused row-norm + GEMM + dist ----------------
// grid = 64 batches * (128/64) * (256/64) = 512 blocks, 256 threads.
// Each block computes a 64x64 tile of dist[b] = 1 - (A@B^T) * invnormA * invnormB.
// Row sum-of-squares is accumulated during global staging (each thread owns
// one row's 4-of-every-16 columns), so no separate normalization pass.
__global__ __launch_bounds__(256) void gemm_dist_kernel(
    const float* __restrict__ seq1,
    const float* __restrict__ seq2,
    float* __restrict__ dist)
{
    const int bid = blockIdx.x;
    const int b   = bid >> 3;
    const int mt  = (bid >> 2) & 1;
    const int nt  = bid & 3;
    const int t   = threadIdx.x;

    const float* Abase = seq1 + (size_t)b * (L1n * Kn) + (size_t)(mt * 64) * Kn;
    const float* Bbase = seq2 + (size_t)b * (L2n * Kn) + (size_t)(nt * 64) * Kn;

    __shared__ float sA[16][68];   // [k][m], padded to dodge bank conflicts
    __shared__ float sB[16][68];   // [k][n]
    __shared__ float sInvA[64];
    __shared__ float sInvB[64];

    const int lrow = t >> 2;         // 0..63  (tile row this thread stages)
    const int lk4  = (t & 3) << 2;   // 0,4,8,12 (column offset in 16-wide K slice)
    const int ty   = t >> 4;         // 0..15
    const int tx   = t & 15;         // 0..15

    float acc[4][4];
#pragma unroll
    for (int i = 0; i < 4; ++i)
#pragma unroll
        for (int j = 0; j < 4; ++j) acc[i][j] = 0.0f;

    float ssA = 0.0f, ssB = 0.0f;

    const float* Aptr = Abase + (size_t)lrow * Kn + lk4;
    const float* Bptr = Bbase + (size_t)lrow * Kn + lk4;

    for (int k0 = 0; k0 < Kn; k0 += 16) {
        float4 a4 = *reinterpret_cast<const float4*>(Aptr + k0);
        float4 b4 = *reinterpret_cast<const float4*>(Bptr + k0);
        ssA += a4.x * a4.x + a4.y * a4.y + a4.z * a4.z + a4.w * a4.w;
        ssB += b4.x * b4.x + b4.y * b4.y + b4.z * b4.z + b4.w * b4.w;

        __syncthreads();            // prior inner-loop reads complete
        sA[lk4 + 0][lrow] = a4.x;
        sA[lk4 + 1][lrow] = a4.y;
        sA[lk4 + 2][lrow] = a4.z;
        sA[lk4 + 3][lrow] = a4.w;
        sB[lk4 + 0][lrow] = b4.x;
        sB[lk4 + 1][lrow] = b4.y;
        sB[lk4 + 2][lrow] = b4.z;
        sB[lk4 + 3][lrow] = b4.w;
        __syncthreads();

#pragma unroll
        for (int kk = 0; kk < 16; ++kk) {
            float4 av = *reinterpret_cast<const float4*>(&sA[kk][ty << 2]);
            float4 bv = *reinterpret_cast<const float4*>(&sB[kk][tx << 2]);
            float aa[4] = {av.x, av.y, av.z, av.w};
            float bb[4] = {bv.x, bv.y, bv.z, bv.w};
#pragma unroll
            for (int i = 0; i < 4; ++i)
#pragma unroll
                for (int j = 0; j < 4; ++j)
                    acc[i][j] += aa[i] * bb[j];
        }
    }

    // Reduce row sum-of-squares across the 4 threads sharing a row
    // (lanes 4m..4m+3 are always within one wave).
    ssA += __shfl_xor(ssA, 1);
    ssA += __shfl_xor(ssA, 2);
    ssB += __shfl_xor(ssB, 1);
    ssB += __shfl_xor(ssB, 2);
    if ((t & 3) == 0) {
        sInvA[lrow] = 1.0f / sqrtf(ssA);
        sInvB[lrow] = 1.0f / sqrtf(ssB);
    }
    __syncthreads();

    float ia[4], ib[4];
#pragma unroll
    for (int i = 0; i < 4; ++i) ia[i] = sInvA[(ty << 2) + i];
#pragma unroll
    for (int j = 0; j < 4; ++j) ib[j] = sInvB[(tx << 2) + j];

    float* drow = dist + ((size_t)b * L1n + mt * 64 + (ty << 2)) * L2n
                       + nt * 64 + (tx << 2);
#pragma unroll
    for (int i = 0; i < 4; ++i) {
        float4 o;
        o.x = 1.0f - acc[i][0] * ia[i] * ib[0];
        o.y = 1.0f - acc[i][1] * ia[i] * ib[1];
        o.z = 1.0f - acc[i][2] * ia[i] * ib[2];
        o.w = 1.0f - acc[i][3] * ia[i] * ib[3];
        *reinterpret_cast<float4*>(drow + (size_t)i * L2n) = o;
    }
}

// ---------------- Kernel 2: DTW wavefront, one wave per batch ----------------
// Anti-diagonal recurrence: cell(i,j) dep on (i,j-1),(i-1,j),(i-1,j-1).
// Lane l owns rows 2l and 2l+1; all cross-lane deps via shfl_up (no barriers).
// dist[b] (128 KB) staged in LDS.
__global__ __launch_bounds__(64) void dtw_kernel(
    const float* __restrict__ dist, float* __restrict__ out)
{
    __shared__ float sd[L1n * L2n];   // 128 KB (gfx950 workgroup LDS max 160 KB)
    const int b    = blockIdx.x;
    const int lane = threadIdx.x;
    const float* src = dist + (size_t)b * (L1n * L2n);

    const float4* s4 = reinterpret_cast<const float4*>(src);
    float4* d4 = reinterpret_cast<float4*>(sd);
#pragma unroll 16
    for (int it = 0; it < 128; ++it)
        d4[it * 64 + lane] = s4[it * 64 + lane];
    __syncthreads();

    const int r0 = lane * 2;
    const int r1 = r0 + 1;
    const float INF = 3.0e38f;
    float c0 = 0.0f, c1 = 0.0f;   // diag k-1 values for rows r0, r1
    float d0p = 0.0f, d1p = 0.0f; // diag k-2 values

    for (int k = 0; k < L1n + L2n - 1; ++k) {
        // neighbor (lane-1) owns row r0-1: its c1/d1p are our up/updiag for r0
        float up0 = __shfl_up(c1, 1);
        float ug0 = __shfl_up(d1p, 1);
        const int j0 = k - r0;
        const int j1 = k - r1;

        // row r0
        float left0 = (j0 >= 1) ? c0 : INF;
        float u0    = (r0 >= 1) ? up0 : INF;
        float g0    = (r0 >= 1 && j0 >= 1) ? ug0 : INF;
        int jc0 = j0 < 0 ? 0 : (j0 > L2n - 1 ? L2n - 1 : j0);
        float m0 = fminf(fminf(left0, u0), g0);
        if (r0 == 0 && j0 == 0) m0 = 0.0f;   // cell(0,0) = dist[0][0]
        float n0 = sd[r0 * L2n + jc0] + m0;

        // row r1 (deps on own row r0 regs: no shuffle)
        float left1 = (j1 >= 1) ? c1 : INF;
        float u1    = c0;                    // cell(r0, j1), r1>=1 always
        float g1    = (j1 >= 1) ? d0p : INF; // cell(r0, j1-1)
        int jc1 = j1 < 0 ? 0 : (j1 > L2n - 1 ? L2n - 1 : j1);
        float m1 = fminf(fminf(left1, u1), g1);
        float n1 = sd[r1 * L2n + jc1] + m1;

        d0p = c0; d1p = c1;
        c0 = n0;  c1 = n1;
    }

    // cell(127,255) lands in lane 63's c1 after k=382
    if (lane == 63)
        out[b] = 1.0f / (1.0f + c1 * (1.0f / (float)(L1n + L2n)));
}

extern "C" void kernel_launch(void* const* d_in, const int* in_sizes, int n_in,
                              void* d_out, int out_size, void* d_ws, size_t ws_size,
                              hipStream_t stream) {
    const float* seq1 = (const float*)d_in[0];   // 64*128*1024
    const float* seq2 = (const float*)d_in[1];   // 64*256*1024
    float* out  = (float*)d_out;                 // 64
    float* dist = (float*)d_ws;                  // 64*128*256 f32 = 8 MB scratch

    gemm_dist_kernel<<<dim3(512), dim3(256), 0, stream>>>(seq1, seq2, dist);
    dtw_kernel<<<dim3(64), dim3(64), 0, stream>>>(dist, out);
}

// Round 2
// 69.377 us; speedup vs baseline: 1.7288x; 1.7288x over previous
//
#include <hip/hip_runtime.h>
#include <cstddef>

#define L1n 128
#define L2n 256
#define Kn  1024
#define BK  64
#define NSTEP (Kn / BK)   // 16

using frag_ab = __attribute__((ext_vector_type(8))) short;  // 8 bf16
using frag_cd = __attribute__((ext_vector_type(4))) float;  // 4 f32

// RNE f32->bf16 pair pack (low, high)
__device__ __forceinline__ unsigned pack_bf16(float x, float y) {
    unsigned ux = __float_as_uint(x);
    ux = (ux + 0x7FFFu + ((ux >> 16) & 1u)) >> 16;
    unsigned uy = __float_as_uint(y);
    uy = (uy + 0x7FFFu + ((uy >> 16) & 1u)) & 0xFFFF0000u;
    return ux | uy;
}

// ---------------- Kernel 1: fused row-norm + bf16-MFMA GEMM + dist ----------------
// grid = 64 batches * 2 * 4 = 512 blocks (2/CU), 256 threads (4 waves, 2x2).
// Block computes a 64x64 tile of dist[b] = 1 - (A@B^T)*invA*invB.
// f32 loads are converted to bf16 into XOR-swizzled LDS (conflict-free
// ds_read_b128 fragment reads); row sum-of-squares accumulated in f32 during
// staging. Double-buffered LDS, loads issued before the MFMA phase.
__global__ __launch_bounds__(256) void gemm_dist_kernel(
    const float* __restrict__ seq1,
    const float* __restrict__ seq2,
    float* __restrict__ dist)
{
    __shared__ __align__(16) unsigned char sA[2][64 * 128];  // 64 rows x 128 B (64 bf16)
    __shared__ __align__(16) unsigned char sB[2][64 * 128];
    __shared__ float sInvA[64];
    __shared__ float sInvB[64];

    // bijective XCD-chunk swizzle: 8 blocks of one batch land on one XCD
    const int wg   = ((blockIdx.x & 7) << 6) + (blockIdx.x >> 3);
    const int b    = wg >> 3;
    const int mt   = (wg >> 2) & 1;
    const int nt   = wg & 3;
    const int t    = threadIdx.x;
    const int lane = t & 63;
    const int w    = t >> 6;
    const int wr   = w >> 1;   // wave row 0..1
    const int wc   = w & 1;    // wave col 0..1

    const int r = t >> 2;      // staging row 0..63 (both A and B)
    const int j = t & 3;       // chunk id 0..3

    const float4* pA = reinterpret_cast<const float4*>(
        seq1 + (size_t)b * (L1n * Kn) + (size_t)(mt * 64 + r) * Kn) + j;
    const float4* pB = reinterpret_cast<const float4*>(
        seq2 + (size_t)b * (L2n * Kn) + (size_t)(nt * 64 + r) * Kn) + j;

    const int swz = (r & 7) << 4;

    float ssA = 0.0f, ssB = 0.0f;
    frag_cd acc[2][2] = {};

    float4 av[4], bv[4];
#pragma unroll
    for (int i = 0; i < 4; ++i) { av[i] = pA[4 * i]; bv[i] = pB[4 * i]; }

    // stage step 0 into buf 0
#pragma unroll
    for (int i = 0; i < 4; ++i) {
        ssA += av[i].x * av[i].x + av[i].y * av[i].y + av[i].z * av[i].z + av[i].w * av[i].w;
        ssB += bv[i].x * bv[i].x + bv[i].y * bv[i].y + bv[i].z * bv[i].z + bv[i].w * bv[i].w;
        const int kb = (j + 4 * i) * 8;
        *reinterpret_cast<uint2*>(&sA[0][r * 128 + (kb ^ swz)]) =
            make_uint2(pack_bf16(av[i].x, av[i].y), pack_bf16(av[i].z, av[i].w));
        *reinterpret_cast<uint2*>(&sB[0][r * 128 + (kb ^ swz)]) =
            make_uint2(pack_bf16(bv[i].x, bv[i].y), pack_bf16(bv[i].z, bv[i].w));
    }

    for (int s = 0; s < NSTEP; ++s) {
        __syncthreads();
        const int cur = s & 1;

        // issue next step's global loads early (latency hides under MFMA)
        if (s + 1 < NSTEP) {
#pragma unroll
            for (int i = 0; i < 4; ++i) {
                av[i] = pA[(s + 1) * 16 + 4 * i];
                bv[i] = pB[(s + 1) * 16 + 4 * i];
            }
        }

        // compute on buf cur: 8 ds_read_b128 + 8 MFMA
#pragma unroll
        for (int kk = 0; kk < 2; ++kk) {
            const int kb = kk * 64 + ((lane >> 4) << 4);
            const int m0 = wr * 32 + (lane & 15);
            const int n0 = wc * 32 + (lane & 15);
            const int fswz = ((lane & 7) << 4);   // (m0&7)<<4 == (lane&7)<<4
            frag_ab a0 = *reinterpret_cast<const frag_ab*>(&sA[cur][m0 * 128 + (kb ^ fswz)]);
            frag_ab a1 = *reinterpret_cast<const frag_ab*>(&sA[cur][(m0 + 16) * 128 + (kb ^ fswz)]);
            frag_ab b0 = *reinterpret_cast<const frag_ab*>(&sB[cur][n0 * 128 + (kb ^ fswz)]);
            frag_ab b1 = *reinterpret_cast<const frag_ab*>(&sB[cur][(n0 + 16) * 128 + (kb ^ fswz)]);
            acc[0][0] = __builtin_amdgcn_mfma_f32_16x16x32_bf16(a0, b0, acc[0][0], 0, 0, 0);
            acc[0][1] = __builtin_amdgcn_mfma_f32_16x16x32_bf16(a0, b1, acc[0][1], 0, 0, 0);
            acc[1][0] = __builtin_amdgcn_mfma_f32_16x16x32_bf16(a1, b0, acc[1][0], 0, 0, 0);
            acc[1][1] = __builtin_amdgcn_mfma_f32_16x16x32_bf16(a1, b1, acc[1][1], 0, 0, 0);
        }

        // convert + write next step into the other buffer
        if (s + 1 < NSTEP) {
            const int nxt = cur ^ 1;
#pragma unroll
            for (int i = 0; i < 4; ++i) {
                ssA += av[i].x * av[i].x + av[i].y * av[i].y + av[i].z * av[i].z + av[i].w * av[i].w;
                ssB += bv[i].x * bv[i].x + bv[i].y * bv[i].y + bv[i].z * bv[i].z + bv[i].w * bv[i].w;
                const int kb = (j + 4 * i) * 8;
                *reinterpret_cast<uint2*>(&sA[nxt][r * 128 + (kb ^ swz)]) =
                    make_uint2(pack_bf16(av[i].x, av[i].y), pack_bf16(av[i].z, av[i].w));
                *reinterpret_cast<uint2*>(&sB[nxt][r * 128 + (kb ^ swz)]) =
                    make_uint2(pack_bf16(bv[i].x, bv[i].y), pack_bf16(bv[i].z, bv[i].w));
            }
        }
    }

    // full-row sum of squares: reduce across the 4 staging threads per row
    ssA += __shfl_xor(ssA, 1); ssA += __shfl_xor(ssA, 2);
    ssB += __shfl_xor(ssB, 1); ssB += __shfl_xor(ssB, 2);
    if (j == 0) { sInvA[r] = rsqrtf(ssA); sInvB[r] = rsqrtf(ssB); }
    __syncthreads();

    // epilogue: dist = 1 - acc * invA[row] * invB[col]
    float* dbase = dist + (size_t)b * (L1n * L2n);
#pragma unroll
    for (int mi = 0; mi < 2; ++mi) {
#pragma unroll
        for (int nj = 0; nj < 2; ++nj) {
            const int row_l = wr * 32 + mi * 16 + ((lane >> 4) << 2);
            const int col_l = wc * 32 + nj * 16 + (lane & 15);
            const float ibv = sInvB[col_l];
            const int gcol = nt * 64 + col_l;
#pragma unroll
            for (int reg = 0; reg < 4; ++reg) {
                const int grow = mt * 64 + row_l + reg;
                dbase[(size_t)grow * L2n + gcol] =
                    1.0f - acc[mi][nj][reg] * sInvA[row_l + reg] * ibv;
            }
        }
    }
}

// ---------------- Kernel 2: DTW wavefront, one wave per batch ----------------
__global__ __launch_bounds__(64) void dtw_kernel(
    const float* __restrict__ dist, float* __restrict__ out)
{
    __shared__ float sd[L1n * L2n];   // 128 KB
    const int b    = blockIdx.x;
    const int lane = threadIdx.x;
    const float* src = dist + (size_t)b * (L1n * L2n);

    const float4* s4 = reinterpret_cast<const float4*>(src);
    float4* d4 = reinterpret_cast<float4*>(sd);
#pragma unroll 16
    for (int it = 0; it < 128; ++it)
        d4[it * 64 + lane] = s4[it * 64 + lane];
    __syncthreads();

    const int r0 = lane * 2;
    const int r1 = r0 + 1;
    const float INF = 3.0e38f;
    float c0 = 0.0f, c1 = 0.0f;   // diag k-1 values for rows r0, r1
    float d0p = 0.0f, d1p = 0.0f; // diag k-2 values

    for (int k = 0; k < L1n + L2n - 1; ++k) {
        float up0 = __shfl_up(c1, 1);
        float ug0 = __shfl_up(d1p, 1);
        const int j0 = k - r0;
        const int j1 = k - r1;

        float left0 = (j0 >= 1) ? c0 : INF;
        float u0    = (r0 >= 1) ? up0 : INF;
        float g0    = (r0 >= 1 && j0 >= 1) ? ug0 : INF;
        int jc0 = j0 < 0 ? 0 : (j0 > L2n - 1 ? L2n - 1 : j0);
        float m0 = fminf(fminf(left0, u0), g0);
        if (r0 == 0 && j0 == 0) m0 = 0.0f;
        float n0 = sd[r0 * L2n + jc0] + m0;

        float left1 = (j1 >= 1) ? c1 : INF;
        float u1    = c0;
        float g1    = (j1 >= 1) ? d0p : INF;
        int jc1 = j1 < 0 ? 0 : (j1 > L2n - 1 ? L2n - 1 : j1);
        float m1 = fminf(fminf(left1, u1), g1);
        float n1 = sd[r1 * L2n + jc1] + m1;

        d0p = c0; d1p = c1;
        c0 = n0;  c1 = n1;
    }

    if (lane == 63)
        out[b] = 1.0f / (1.0f + c1 * (1.0f / (float)(L1n + L2n)));
}

extern "C" void kernel_launch(void* const* d_in, const int* in_sizes, int n_in,
                              void* d_out, int out_size, void* d_ws, size_t ws_size,
                              hipStream_t stream) {
    const float* seq1 = (const float*)d_in[0];   // 64*128*1024 f32
    const float* seq2 = (const float*)d_in[1];   // 64*256*1024 f32
    float* out  = (float*)d_out;                 // 64 f32
    float* dist = (float*)d_ws;                  // 64*128*256 f32 = 8 MB scratch

    gemm_dist_kernel<<<dim3(512), dim3(256), 0, stream>>>(seq1, seq2, dist);
    dtw_kernel<<<dim3(64), dim3(64), 0, stream>>>(dist, out);
}

// Round 3
// 53.995 us; speedup vs baseline: 2.2213x; 1.2849x over previous
//
#include <hip/hip_runtime.h>
#include <cstddef>

#define L1n 128
#define L2n 256
#define Kn  1024
#define BK  64
#define NSTEP (Kn / BK)   // 16
#define LAG  4
#define DTW_STEPS (L2n + LAG * 63)   // 508

using frag_ab = __attribute__((ext_vector_type(8))) short;  // 8 bf16
using frag_cd = __attribute__((ext_vector_type(4))) float;  // 4 f32

// RNE f32->bf16 pair pack (low, high)
__device__ __forceinline__ unsigned pack_bf16(float x, float y) {
    unsigned ux = __float_as_uint(x);
    ux = (ux + 0x7FFFu + ((ux >> 16) & 1u)) >> 16;
    unsigned uy = __float_as_uint(y);
    uy = (uy + 0x7FFFu + ((uy >> 16) & 1u)) & 0xFFFF0000u;
    return ux | uy;
}

// ---------------- Kernel 1: fused row-norm + bf16-MFMA GEMM + dist ----------------
// grid = 512 blocks, 256 threads. 64x64 tile of dist = 1 - (A@B^T)*invA*invB.
// Writes dist TRANSPOSED: dist_t[b][col][row] so the DTW column sweep reads
// each lane's (row-pair, col) as one ds_read_b64.
__global__ __launch_bounds__(256) void gemm_dist_kernel(
    const float* __restrict__ seq1,
    const float* __restrict__ seq2,
    float* __restrict__ dist)
{
    __shared__ __align__(16) unsigned char sA[2][64 * 128];
    __shared__ __align__(16) unsigned char sB[2][64 * 128];
    __shared__ float sInvA[64];
    __shared__ float sInvB[64];

    const int wg   = ((blockIdx.x & 7) << 6) + (blockIdx.x >> 3);
    const int b    = wg >> 3;
    const int mt   = (wg >> 2) & 1;
    const int nt   = wg & 3;
    const int t    = threadIdx.x;
    const int lane = t & 63;
    const int w    = t >> 6;
    const int wr   = w >> 1;
    const int wc   = w & 1;

    const int r = t >> 2;
    const int j = t & 3;

    const float4* pA = reinterpret_cast<const float4*>(
        seq1 + (size_t)b * (L1n * Kn) + (size_t)(mt * 64 + r) * Kn) + j;
    const float4* pB = reinterpret_cast<const float4*>(
        seq2 + (size_t)b * (L2n * Kn) + (size_t)(nt * 64 + r) * Kn) + j;

    const int swz = (r & 7) << 4;

    float ssA = 0.0f, ssB = 0.0f;
    frag_cd acc[2][2] = {};

    float4 av[4], bv[4];
#pragma unroll
    for (int i = 0; i < 4; ++i) { av[i] = pA[4 * i]; bv[i] = pB[4 * i]; }

#pragma unroll
    for (int i = 0; i < 4; ++i) {
        ssA += av[i].x * av[i].x + av[i].y * av[i].y + av[i].z * av[i].z + av[i].w * av[i].w;
        ssB += bv[i].x * bv[i].x + bv[i].y * bv[i].y + bv[i].z * bv[i].z + bv[i].w * bv[i].w;
        const int kb = (j + 4 * i) * 8;
        *reinterpret_cast<uint2*>(&sA[0][r * 128 + (kb ^ swz)]) =
            make_uint2(pack_bf16(av[i].x, av[i].y), pack_bf16(av[i].z, av[i].w));
        *reinterpret_cast<uint2*>(&sB[0][r * 128 + (kb ^ swz)]) =
            make_uint2(pack_bf16(bv[i].x, bv[i].y), pack_bf16(bv[i].z, bv[i].w));
    }

    for (int s = 0; s < NSTEP; ++s) {
        __syncthreads();
        const int cur = s & 1;

        if (s + 1 < NSTEP) {
#pragma unroll
            for (int i = 0; i < 4; ++i) {
                av[i] = pA[(s + 1) * 16 + 4 * i];
                bv[i] = pB[(s + 1) * 16 + 4 * i];
            }
        }

#pragma unroll
        for (int kk = 0; kk < 2; ++kk) {
            const int kb = kk * 64 + ((lane >> 4) << 4);
            const int m0 = wr * 32 + (lane & 15);
            const int n0 = wc * 32 + (lane & 15);
            const int fswz = ((lane & 7) << 4);
            frag_ab a0 = *reinterpret_cast<const frag_ab*>(&sA[cur][m0 * 128 + (kb ^ fswz)]);
            frag_ab a1 = *reinterpret_cast<const frag_ab*>(&sA[cur][(m0 + 16) * 128 + (kb ^ fswz)]);
            frag_ab b0 = *reinterpret_cast<const frag_ab*>(&sB[cur][n0 * 128 + (kb ^ fswz)]);
            frag_ab b1 = *reinterpret_cast<const frag_ab*>(&sB[cur][(n0 + 16) * 128 + (kb ^ fswz)]);
            acc[0][0] = __builtin_amdgcn_mfma_f32_16x16x32_bf16(a0, b0, acc[0][0], 0, 0, 0);
            acc[0][1] = __builtin_amdgcn_mfma_f32_16x16x32_bf16(a0, b1, acc[0][1], 0, 0, 0);
            acc[1][0] = __builtin_amdgcn_mfma_f32_16x16x32_bf16(a1, b0, acc[1][0], 0, 0, 0);
            acc[1][1] = __builtin_amdgcn_mfma_f32_16x16x32_bf16(a1, b1, acc[1][1], 0, 0, 0);
        }

        if (s + 1 < NSTEP) {
            const int nxt = cur ^ 1;
#pragma unroll
            for (int i = 0; i < 4; ++i) {
                ssA += av[i].x * av[i].x + av[i].y * av[i].y + av[i].z * av[i].z + av[i].w * av[i].w;
                ssB += bv[i].x * bv[i].x + bv[i].y * bv[i].y + bv[i].z * bv[i].z + bv[i].w * bv[i].w;
                const int kb = (j + 4 * i) * 8;
                *reinterpret_cast<uint2*>(&sA[nxt][r * 128 + (kb ^ swz)]) =
                    make_uint2(pack_bf16(av[i].x, av[i].y), pack_bf16(av[i].z, av[i].w));
                *reinterpret_cast<uint2*>(&sB[nxt][r * 128 + (kb ^ swz)]) =
                    make_uint2(pack_bf16(bv[i].x, bv[i].y), pack_bf16(bv[i].z, bv[i].w));
            }
        }
    }

    ssA += __shfl_xor(ssA, 1); ssA += __shfl_xor(ssA, 2);
    ssB += __shfl_xor(ssB, 1); ssB += __shfl_xor(ssB, 2);
    if (j == 0) { sInvA[r] = rsqrtf(ssA); sInvB[r] = rsqrtf(ssB); }
    __syncthreads();

    // epilogue: dist_t[b][col][row] = 1 - acc * invA[row] * invB[col]
    float* dbase = dist + (size_t)b * (L1n * L2n);
#pragma unroll
    for (int mi = 0; mi < 2; ++mi) {
#pragma unroll
        for (int nj = 0; nj < 2; ++nj) {
            const int row_l = wr * 32 + mi * 16 + ((lane >> 4) << 2);
            const int col_l = wc * 32 + nj * 16 + (lane & 15);
            const float ibv = sInvB[col_l];
            const int gcol = nt * 64 + col_l;
            const int grow = mt * 64 + row_l;
            float4 o;
            o.x = 1.0f - acc[mi][nj][0] * sInvA[row_l + 0] * ibv;
            o.y = 1.0f - acc[mi][nj][1] * sInvA[row_l + 1] * ibv;
            o.z = 1.0f - acc[mi][nj][2] * sInvA[row_l + 2] * ibv;
            o.w = 1.0f - acc[mi][nj][3] * sInvA[row_l + 3] * ibv;
            *reinterpret_cast<float4*>(&dbase[(size_t)gcol * L1n + grow]) = o;
        }
    }
}

// ---------------- Kernel 2: DTW lag-skewed column sweep ----------------
// Lane l owns rows 2l,2l+1, sweeps columns j=0..255 starting LAG*l steps in.
// Cross-lane dep (nb row 2l-1, col j) is produced LAG steps before use ->
// shfl latency off critical path via 4-deep shift register. dist values
// prefetched 8 steps ahead from transposed LDS.
__global__ __launch_bounds__(64) void dtw_kernel(
    const float* __restrict__ dist, float* __restrict__ out)
{
    __shared__ float sd[L2n * L1n];   // [col][row], 128 KB
    const int b    = blockIdx.x;
    const int lane = threadIdx.x;
    const float* src = dist + (size_t)b * (L1n * L2n);

    const float4* s4 = reinterpret_cast<const float4*>(src);
    float4* d4 = reinterpret_cast<float4*>(sd);
#pragma unroll 8
    for (int it = 0; it < 128; ++it)
        d4[it * 64 + lane] = s4[it * 64 + lane];
    __syncthreads();

    const int r0 = lane * 2;
    const bool lane0 = (lane == 0);
    const float INF = 3.0e38f;

    float c0 = INF, c1 = INF;                 // D(r0,j-1), D(r1,j-1)
    float sh0 = INF, sh1 = INF, sh2 = INF, sh3 = INF;  // shfl pipe, sh3 = issued t-LAG
    float ug = INF;                           // issued t-LAG-1

    auto ldval = [&](int tt) -> float2 {
        int jj = tt - LAG * lane;
        jj = jj < 0 ? 0 : (jj > L2n - 1 ? L2n - 1 : jj);
        return *reinterpret_cast<const float2*>(&sd[jj * L1n + r0]);
    };

    auto step = [&](int tt, float2 d) {
        const int jj = tt - LAG * lane;
        const bool jpos = (jj >= 1);
        float up0   = lane0 ? INF : sh3;
        float g0    = (lane0 || !jpos) ? INF : ug;
        float left0 = jpos ? c0 : INF;
        float m0 = fminf(fminf(left0, up0), g0);
        m0 = (lane0 && jj == 0) ? 0.0f : m0;
        float n0 = d.x + m0;
        float left1 = jpos ? c1 : INF;
        float g1    = jpos ? c0 : INF;
        float m1 = fminf(fminf(left1, n0), g1);
        float n1 = d.y + m1;
        float snew = __shfl_up(n1, 1);
        ug = sh3; sh3 = sh2; sh2 = sh1; sh1 = sh0; sh0 = snew;
        c0 = n0; c1 = n1;
    };

    float2 pf[8];
#pragma unroll
    for (int u = 0; u < 8; ++u) pf[u] = ldval(u);

    int t = 0;
    for (int blk = 0; blk < 63; ++blk) {      // 504 steps
        float2 cur[8];
#pragma unroll
        for (int u = 0; u < 8; ++u) cur[u] = pf[u];
#pragma unroll
        for (int u = 0; u < 8; ++u) pf[u] = ldval(t + 8 + u);
#pragma unroll
        for (int u = 0; u < 8; ++u) step(t + u, cur[u]);
        t += 8;
    }
#pragma unroll
    for (int u = 0; u < 4; ++u) step(t + u, pf[u]);   // steps 504..507

    // lane 63 finishes (127,255) at t=507 -> c1
    if (lane == 63)
        out[b] = 1.0f / (1.0f + c1 * (1.0f / (float)(L1n + L2n)));
}

extern "C" void kernel_launch(void* const* d_in, const int* in_sizes, int n_in,
                              void* d_out, int out_size, void* d_ws, size_t ws_size,
                              hipStream_t stream) {
    const float* seq1 = (const float*)d_in[0];   // 64*128*1024 f32
    const float* seq2 = (const float*)d_in[1];   // 64*256*1024 f32
    float* out  = (float*)d_out;                 // 64 f32
    float* dist = (float*)d_ws;                  // 8 MB scratch (transposed dist)

    gemm_dist_kernel<<<dim3(512), dim3(256), 0, stream>>>(seq1, seq2, dist);
    dtw_kernel<<<dim3(64), dim3(64), 0, stream>>>(dist, out);
}